// Round 7
// baseline (856457.812 us; speedup 1.0000x reference)
//
#include <hip/hip_runtime.h>

#define B_   64
#define T_   512
#define D_   512
#define H_   1024
#define G4   4096      // 4*H
#define KC_N 48        // (D+H)/32 k-chunks
#define NG   8         // row-groups (1 per XCD ideally)
#define CPG  32        // col-blocks per group
#define RPG  8         // batch rows per group
#define NBLK 256

typedef float f32x4 __attribute__((ext_vector_type(4)));
typedef short s16x8 __attribute__((ext_vector_type(8)));

__device__ __forceinline__ unsigned short f2bf(float f) {
    unsigned int u = __float_as_uint(f);
    u = (u + 0x7fffu + ((u >> 16) & 1u)) >> 16;   // RNE
    return (unsigned short)u;
}
__device__ __forceinline__ float sigm(float x) { return 1.f / (1.f + __expf(-x)); }
__device__ __forceinline__ float tanh_f(float x) { return 1.f - 2.f / (__expf(2.f * x) + 1.f); }

__device__ __forceinline__ s16x8 cvt8(float4 a, float4 b) {
    union { s16x8 v; unsigned int u[4]; } r;
    asm("v_cvt_pk_bf16_f32 %0, %1, %2" : "=v"(r.u[0]) : "v"(a.x), "v"(a.y));
    asm("v_cvt_pk_bf16_f32 %0, %1, %2" : "=v"(r.u[1]) : "v"(a.z), "v"(a.w));
    asm("v_cvt_pk_bf16_f32 %0, %1, %2" : "=v"(r.u[2]) : "v"(b.x), "v"(b.y));
    asm("v_cvt_pk_bf16_f32 %0, %1, %2" : "=v"(r.u[3]) : "v"(b.z), "v"(b.w));
    return r.v;
}

// Pack [W_ih | W_hh] into MFMA B-fragment order (unchanged from R3):
// Wpk[(((c16*48 + kc)*64 + lane))*8 + j] = W[row(n)][k], n = c16*16 + (lane&15),
// k = kc*32 + (lane>>4)*8 + j; packed col n = 4*j_hidden + gate.
__global__ __launch_bounds__(256) void pack_w(const float* __restrict__ W_ih,
                                              const float* __restrict__ W_hh,
                                              unsigned short* __restrict__ Wpk) {
    int tid = blockIdx.x * 256 + threadIdx.x;
    int j    = tid & 7;
    int lane = (tid >> 3) & 63;
    int rest = tid >> 9;
    int kc = rest % KC_N;
    int c  = rest / KC_N;
    int npk = c * 16 + (lane & 15);
    int jh = npk >> 2, g = npk & 3;
    int row = g * H_ + jh;
    int k = kc * 32 + (lane >> 4) * 8 + j;
    float v = (k < D_) ? W_ih[row * D_ + k] : W_hh[row * H_ + (k - D_)];
    Wpk[tid] = f2bf(v);
}

// hbuf layout: [parity][group][row 0..8][unit 0..1024] bf16
__global__ __launch_bounds__(256) void init_state3(
    const float* __restrict__ h0, const float* __restrict__ b_ih,
    const float* __restrict__ b_hh, unsigned short* __restrict__ hbuf,
    float* __restrict__ bias_p, unsigned int* __restrict__ flags,
    unsigned int* __restrict__ setup)
{
    int tid = blockIdx.x * 256 + threadIdx.x;        // grid 512*256 = 131072
    int unit = tid & (H_ - 1);
    hbuf[tid] = f2bf(h0[unit]);                      // covers both parities
    if (tid < G4) {
        int jh = tid >> 2, g = tid & 3;
        bias_p[tid] = b_ih[g * H_ + jh] + b_hh[g * H_ + jh];
    }
    if (tid < 1024) flags[tid] = 0u;                 // [g][c][epi-wave]
    if (tid < 32)   setup[tid] = 0u;                 // claim state
}

// Persistent LSTM, XCD-local exchange.
// group g = 8 batch rows, served by 32 blocks (ideally all on XCD g).
// block (g,c): 128 packed cols = 32 hidden units, M=8 (16-row MFMA, rows 8-15
// are duplicates whose outputs are never stored). 8 waves = K-slices:
// wave w: x-kc {2w,2w+1} (W_ih streamed from L2), h-kc {16+4w..+4} (W_hh pinned).
// Fast path (group fully XCD-local): h + flags via plain stores / sc0 loads —
// all traffic stays in the XCD's L2. Slow path (any remote member): R3's
// agent-scope protocol. Claiming via XCC_ID + device atomics, any mapping safe.
__global__ __launch_bounds__(512) void lstm_persist(
    const float* __restrict__ x, const int* __restrict__ mask,
    const unsigned short* __restrict__ Wpk, const float* __restrict__ bias_p,
    const float* __restrict__ h0, const float* __restrict__ c0,
    unsigned short* __restrict__ hbuf, float* __restrict__ out,
    unsigned int* __restrict__ flags, unsigned int* __restrict__ setup)
{
    const int tid = threadIdx.x;
    const int w = tid >> 6, l = tid & 63;
    const int quad = l >> 4, l15 = l & 15;

    __shared__ float Dls[8][8][132];     // [wave][row][col], padded
    __shared__ int sb_work, sb_fast;

    // ---- one-time work claiming (tid 0) ----
    if (tid == 0) {
        unsigned int xcd;
        asm volatile("s_getreg_b32 %0, hwreg(HW_REG_XCC_ID)" : "=s"(xcd));
        xcd &= 7u;
        unsigned int slot = __hip_atomic_fetch_add(&setup[xcd], 1u,
                                __ATOMIC_RELAXED, __HIP_MEMORY_SCOPE_AGENT);
        int wk = -1;
        if (slot < CPG) wk = (int)(xcd * CPG + slot);
        __hip_atomic_fetch_add(&setup[8], 1u, __ATOMIC_RELAXED, __HIP_MEMORY_SCOPE_AGENT);
        int gd = 0;
        while (__hip_atomic_load(&setup[8], __ATOMIC_RELAXED,
                                 __HIP_MEMORY_SCOPE_AGENT) < NBLK) {
            __builtin_amdgcn_s_sleep(8);
            if (++gd > (1 << 20)) break;
        }
        if (wk < 0) {                     // overflow: take an unclaimed item
            unsigned int r = __hip_atomic_fetch_add(&setup[10], 1u,
                                 __ATOMIC_RELAXED, __HIP_MEMORY_SCOPE_AGENT);
            unsigned int acc2 = 0;
            for (int gg = 0; gg < NG; ++gg) {
                unsigned int cg = __hip_atomic_load(&setup[gg], __ATOMIC_RELAXED,
                                                    __HIP_MEMORY_SCOPE_AGENT);
                unsigned int cl = cg > CPG ? CPG : cg;
                unsigned int un = CPG - cl;
                if (r < acc2 + un) { wk = gg * CPG + (int)(cl + (r - acc2)); break; }
                acc2 += un;
            }
            if (wk < 0) wk = 0;           // paranoid
            __hip_atomic_fetch_or(&setup[11], 1u << (wk / CPG),
                                  __ATOMIC_RELAXED, __HIP_MEMORY_SCOPE_AGENT);
        }
        __hip_atomic_fetch_add(&setup[9], 1u, __ATOMIC_RELAXED, __HIP_MEMORY_SCOPE_AGENT);
        gd = 0;
        while (__hip_atomic_load(&setup[9], __ATOMIC_RELAXED,
                                 __HIP_MEMORY_SCOPE_AGENT) < NBLK) {
            __builtin_amdgcn_s_sleep(8);
            if (++gd > (1 << 20)) break;
        }
        unsigned int rm = __hip_atomic_load(&setup[11], __ATOMIC_RELAXED,
                                            __HIP_MEMORY_SCOPE_AGENT);
        sb_work = wk;
        sb_fast = ((rm >> (wk / CPG)) & 1u) ? 0 : 1;
    }
    __syncthreads();
    const int wk = sb_work, fast = sb_fast;
    const int g = wk >> 5;               // /CPG
    const int c = wk & 31;

    // ---- pinned W_hh fragments: 8 colgroups x 4 h-kc (128 VGPR/lane) ----
    s16x8 Bh[8][4];
    #pragma unroll
    for (int n = 0; n < 8; ++n) {
        const unsigned short* cb = Wpk + (size_t)((c * 8 + n) * KC_N) * 512;
        #pragma unroll
        for (int i = 0; i < 4; ++i) {
            int kc = 16 + w * 4 + i;
            Bh[n][i] = *reinterpret_cast<const s16x8*>(cb + (size_t)kc * 512 + l * 8);
        }
    }
    #pragma unroll
    for (int n = 0; n < 8; ++n)
        #pragma unroll
        for (int i = 0; i < 4; ++i)
            asm volatile("" : "+v"(Bh[n][i]));   // liveness pin

    // ---- epilogue state (tid<256): (row er, unit eu) ----
    const int er = tid >> 5, eu = tid & 31;
    const int brow = g * RPG + er;
    const int jcol = c * 32 + eu;
    float c_reg = 0.f, h_reg = 0.f;
    float4 bias = make_float4(0.f, 0.f, 0.f, 0.f);
    if (tid < 256) {
        c_reg = c0[jcol];
        h_reg = h0[jcol];
        bias = *reinterpret_cast<const float4*>(bias_p + c * 128 + eu * 4);
    }

    const int arow_x = g * RPG + (l15 & 7);          // rows 8-15 duplicate 0-7
    const float* xbase = x + (size_t)arow_x * T_ * D_ + w * 64 + quad * 8;
    const unsigned short* wxb = Wpk + ((size_t)(c * 8) * KC_N + (size_t)(w * 2)) * 512
                                    + (size_t)l * 8;
    const int hrow = l15 & 7;

    #pragma unroll 1
    for (int t = 0; t < T_; ++t) {
        const unsigned short* hin  = hbuf + ((size_t)((t & 1) * NG + g) * RPG) * 1024;
        unsigned short*       hout = hbuf + ((size_t)(((t + 1) & 1) * NG + g) * RPG) * 1024;

        // ---- phase A: x-part MFMA, W_ih streamed (pre-poll, overlapped) ----
        f32x4 acc[8];
        #pragma unroll
        for (int n = 0; n < 8; ++n) acc[n] = (f32x4){0.f, 0.f, 0.f, 0.f};
        int mv = 0;
        if (tid < 256) mv = mask[(size_t)brow * T_ + t];
        const float* xp = xbase + (size_t)t * D_;
        #pragma unroll
        for (int i = 0; i < 2; ++i) {
            s16x8 bx[8];
            #pragma unroll
            for (int n = 0; n < 8; ++n) {
                const void* p = wxb + (size_t)n * (KC_N * 512) + (size_t)i * 512;
                asm volatile("global_load_dwordx4 %0, %1, off" : "=v"(bx[n]) : "v"(p));
            }
            float4 v0 = *reinterpret_cast<const float4*>(xp + i * 32);
            float4 v1 = *reinterpret_cast<const float4*>(xp + i * 32 + 4);
            s16x8 af = cvt8(v0, v1);
            asm volatile("s_waitcnt vmcnt(0)" ::: "memory");
            __builtin_amdgcn_sched_barrier(0);
            #pragma unroll
            for (int n = 0; n < 8; ++n)
                acc[n] = __builtin_amdgcn_mfma_f32_16x16x32_bf16(af, bx[n], acc[n], 0, 0, 0);
        }

        // ---- poll the group's 128 producer flags ----
        if (t > 0) {
            const unsigned int tgt = (unsigned int)t;
            const unsigned int* fp = flags + g * 128 + l;
            int gd = 0;
            if (fast) {
                for (;;) {
                    unsigned int f0, f1;
                    asm volatile("global_load_dword %0, %2, off sc0\n\t"
                                 "global_load_dword %1, %3, off sc0\n\t"
                                 "s_waitcnt vmcnt(0)"
                                 : "=&v"(f0), "=&v"(f1)
                                 : "v"(fp), "v"(fp + 64)
                                 : "memory");
                    if (__all((int)((f0 >= tgt) & (f1 >= tgt)))) break;
                    if (++gd > (1 << 14)) break;
                    __builtin_amdgcn_s_sleep(1);
                }
            } else {
                for (;;) {
                    unsigned int f0 = __hip_atomic_load(fp,      __ATOMIC_RELAXED, __HIP_MEMORY_SCOPE_AGENT);
                    unsigned int f1 = __hip_atomic_load(fp + 64, __ATOMIC_RELAXED, __HIP_MEMORY_SCOPE_AGENT);
                    if (__all((int)((f0 >= tgt) & (f1 >= tgt)))) break;
                    if (++gd > (1 << 14)) break;
                    __builtin_amdgcn_s_sleep(1);
                }
            }
        }
        __builtin_amdgcn_fence(__ATOMIC_ACQUIRE, "workgroup");
        __builtin_amdgcn_sched_barrier(0);

        // ---- phase B: h loads (XCD-L2 fast / LLC slow) + pinned-W_hh MFMA ----
        const unsigned short* hr = hin + (size_t)hrow * 1024 + w * 128 + quad * 8;
        s16x8 hf[4];
        if (fast) {
            #pragma unroll
            for (int i = 0; i < 4; ++i) {
                const void* p = hr + i * 32;
                asm volatile("global_load_dwordx4 %0, %1, off sc0" : "=v"(hf[i]) : "v"(p));
            }
            asm volatile("s_waitcnt vmcnt(0)" ::: "memory");
            __builtin_amdgcn_sched_barrier(0);
        } else {
            #pragma unroll
            for (int i = 0; i < 4; ++i) {
                const unsigned long long* hp =
                    reinterpret_cast<const unsigned long long*>(hr + i * 32);
                union { s16x8 v; unsigned long long q[2]; } au;
                au.q[0] = __hip_atomic_load(hp,     __ATOMIC_RELAXED, __HIP_MEMORY_SCOPE_AGENT);
                au.q[1] = __hip_atomic_load(hp + 1, __ATOMIC_RELAXED, __HIP_MEMORY_SCOPE_AGENT);
                hf[i] = au.v;
            }
        }
        #pragma unroll
        for (int i = 0; i < 4; ++i)
            #pragma unroll
            for (int n = 0; n < 8; ++n)
                acc[n] = __builtin_amdgcn_mfma_f32_16x16x32_bf16(hf[i], Bh[n][i], acc[n], 0, 0, 0);

        // D rows 0-7 only (quad<2); rows 8-15 are duplicate-junk, never stored
        if (quad < 2) {
            #pragma unroll
            for (int n = 0; n < 8; ++n)
                #pragma unroll
                for (int r = 0; r < 4; ++r)
                    Dls[w][quad * 4 + r][n * 16 + l15] = acc[n][r];
        }
        __syncthreads();   // the only block barrier per step

        // ---- epilogue (waves 0-3): reduce 8 k-slices, cell, store, flag ----
        if (tid < 256) {
            f32x4 gsum = (f32x4){0.f, 0.f, 0.f, 0.f};
            #pragma unroll
            for (int ww = 0; ww < 8; ++ww)
                gsum += *reinterpret_cast<f32x4*>(&Dls[ww][er][eu * 4]);
            float gi = sigm  (gsum[0] + bias.x);
            float gf = sigm  (gsum[1] + bias.y);
            float gg = tanh_f(gsum[2] + bias.z);
            float go = sigm  (gsum[3] + bias.w);
            float c_new = gf * c_reg + gi * gg;
            float h_new = go * tanh_f(c_new);
            float h2 = mv ? h_new : h_reg;
            c_reg = mv ? c_new : c_reg;
            h_reg = h2;
            if (t < T_ - 1) {
                unsigned int hv = (unsigned int)f2bf(h2);
                unsigned int hx = (unsigned int)__shfl_xor((int)hv, 1);
                unsigned int pk = (hx << 16) | hv;
                unsigned int* hp = reinterpret_cast<unsigned int*>(
                                       hout + (size_t)er * 1024 + jcol);
                unsigned int* fp = flags + g * 128 + c * 4 + w;   // w = 0..3 here
                if (fast) {
                    if (!(eu & 1)) *(volatile unsigned int*)hp = pk;
                    asm volatile("s_waitcnt vmcnt(0)" ::: "memory");
                    if (l == 0) *(volatile unsigned int*)fp = (unsigned int)(t + 1);
                } else {
                    if (!(eu & 1)) __hip_atomic_store(hp, pk, __ATOMIC_RELAXED,
                                                      __HIP_MEMORY_SCOPE_AGENT);
                    asm volatile("s_waitcnt vmcnt(0)" ::: "memory");
                    if (l == 0) __hip_atomic_store(fp, (unsigned int)(t + 1),
                                                   __ATOMIC_RELAXED, __HIP_MEMORY_SCOPE_AGENT);
                }
            }
            out[((size_t)brow * T_ + t) * H_ + jcol] = h2;   // off critical path
        }
        // waves 4-7 proceed straight to phase A of t+1
    }
}

extern "C" void kernel_launch(void* const* d_in, const int* in_sizes, int n_in,
                              void* d_out, int out_size, void* d_ws, size_t ws_size,
                              hipStream_t stream)
{
    const float* x    = (const float*)d_in[0];
    const int*   mask = (const int*)d_in[1];
    const float* W_ih = (const float*)d_in[2];
    const float* W_hh = (const float*)d_in[3];
    const float* b_ih = (const float*)d_in[4];
    const float* b_hh = (const float*)d_in[5];
    const float* h0   = (const float*)d_in[6];
    const float* c0   = (const float*)d_in[7];
    float* out = (float*)d_out;

    // ws layout (~12.9 MB total)
    char* wsb = (char*)d_ws;
    unsigned short* Wpk    = (unsigned short*)(wsb);             // 12,582,912 B
    float*          bias_p = (float*)(wsb + 12582912);           //     16,384 B
    unsigned short* hbuf   = (unsigned short*)(wsb + 12599296);  //    262,144 B
    unsigned int*   flags  = (unsigned int*)(wsb + 12861440);    //      4,096 B
    unsigned int*   setup  = (unsigned int*)(wsb + 12865536);    //        128 B

    pack_w<<<24576, 256, 0, stream>>>(W_ih, W_hh, Wpk);
    init_state3<<<512, 256, 0, stream>>>(h0, b_ih, b_hh, hbuf, bias_p, flags, setup);
    lstm_persist<<<256, 512, 0, stream>>>(x, mask, Wpk, bias_p, h0, c0, hbuf, out,
                                          flags, setup);
}

// Round 8
// 4715.491 us; speedup vs baseline: 181.6264x; 181.6264x over previous
//
#include <hip/hip_runtime.h>

#define B_   64
#define T_   512
#define D_   512
#define H_   1024
#define G4   4096      // 4*H
#define KC_N 48        // (D+H)/32 k-chunks

typedef float f32x4 __attribute__((ext_vector_type(4)));
typedef short s16x8 __attribute__((ext_vector_type(8)));

__device__ __forceinline__ unsigned short f2bf(float f) {
    unsigned int u = __float_as_uint(f);
    u = (u + 0x7fffu + ((u >> 16) & 1u)) >> 16;   // RNE
    return (unsigned short)u;
}
__device__ __forceinline__ float bf2f(unsigned short h) {
    return __uint_as_float(((unsigned int)h) << 16);
}
__device__ __forceinline__ float sigm(float x) { return 1.f / (1.f + __expf(-x)); }
__device__ __forceinline__ float tanh_f(float x) { return 1.f - 2.f / (__expf(2.f * x) + 1.f); }

// 8x f32 -> 8x bf16 (RNE) via v_cvt_pk_bf16_f32 (lo = src0)
__device__ __forceinline__ s16x8 cvt8(float4 a, float4 b) {
    union { s16x8 v; unsigned int u[4]; } r;
    asm("v_cvt_pk_bf16_f32 %0, %1, %2" : "=v"(r.u[0]) : "v"(a.x), "v"(a.y));
    asm("v_cvt_pk_bf16_f32 %0, %1, %2" : "=v"(r.u[1]) : "v"(a.z), "v"(a.w));
    asm("v_cvt_pk_bf16_f32 %0, %1, %2" : "=v"(r.u[2]) : "v"(b.x), "v"(b.y));
    asm("v_cvt_pk_bf16_f32 %0, %1, %2" : "=v"(r.u[3]) : "v"(b.z), "v"(b.w));
    return r.v;
}

// Pack [W_ih | W_hh] into exact MFMA B-fragment order, bf16, gate-interleaved
// columns (packed col n = 4*j_hidden + gate):
// Wpk[(((c16*48 + kc)*64 + lane))*8 + j] = W[row(n)][k], n = c16*16 + (lane&15),
// k = kc*32 + (lane>>4)*8 + j.
__global__ __launch_bounds__(256) void pack_w(const float* __restrict__ W_ih,
                                              const float* __restrict__ W_hh,
                                              unsigned short* __restrict__ Wpk) {
    int tid = blockIdx.x * 256 + threadIdx.x;        // [0, 256*48*64*8)
    int j    = tid & 7;
    int lane = (tid >> 3) & 63;
    int rest = tid >> 9;
    int kc = rest % KC_N;
    int c  = rest / KC_N;
    int npk = c * 16 + (lane & 15);
    int jh = npk >> 2, g = npk & 3;
    int row = g * H_ + jh;                           // torch gate order i,f,g,o
    int k = kc * 32 + (lane >> 4) * 8 + j;
    float v = (k < D_) ? W_ih[row * D_ + k] : W_hh[row * H_ + (k - D_)];
    Wpk[tid] = f2bf(v);
}

__global__ __launch_bounds__(256) void init_state(const float* __restrict__ h0,
                                                  const float* __restrict__ c0,
                                                  const float* __restrict__ b_ih,
                                                  const float* __restrict__ b_hh,
                                                  unsigned short* __restrict__ h_a,
                                                  float* __restrict__ c_cur,
                                                  float* __restrict__ bias_p) {
    int tid = blockIdx.x * 256 + threadIdx.x;        // 65536
    int j = tid & (H_ - 1);
    h_a[tid]  = f2bf(h0[j]);
    c_cur[tid] = c0[j];
    if (tid < G4) {                                  // bias in packed-col order
        int jh = tid >> 2, g = tid & 3;
        bias_p[tid] = b_ih[g * H_ + jh] + b_hh[g * H_ + jh];
    }
}

// One timestep. Grid (128 colgroups, 2 batch halves), 512 threads (8 waves).
// block = 32 packed cols (8 hidden units) x 32 batch rows.
// wave w = k-slice: kc = w*6 .. w*6+5 (covers BOTH 16-row m-tiles) -> each
// weight fragment is loaded once per block (25 MB/step aggregate, 2x vs the
// old 4x). Linear bid = x + 128*y -> both batch halves of colgroup x land on
// XCD x%8 -> each XCD's weight slice (16 cg x 196 KB = 1.6 MB) is L2-resident.
// No LDS A-staging: x converted in-register (cvt_pk), h loaded bf16x8 direct.
__global__ __launch_bounds__(512) void lstm_step2(
    const float* __restrict__ x, const int* __restrict__ mask,
    const unsigned short* __restrict__ Wpk, const float* __restrict__ bias_p,
    const unsigned short* __restrict__ h_in, unsigned short* __restrict__ h_out,
    float* __restrict__ c_cur, float* __restrict__ out, int t)
{
    const int tid = threadIdx.x;
    const int cg  = blockIdx.x;          // 0..127: 32 packed cols
    const int mh  = blockIdx.y;          // batch half
    const int b0g = mh << 5;

    const int w = tid >> 6, l = tid & 63;
    const int quad = l >> 4, l15 = l & 15;

    __shared__ float Dls[8][32][36];     // [k-slice][m-row][gate-col], padded

    // epilogue mapping (tid<256): thread -> (batch row b_l, hidden unit u)
    const int b_l = tid >> 3, u = tid & 7;
    const int brow = b0g + b_l;
    const int jcol = cg * 8 + u;

    // early independent loads (epilogue state) — issue before the MFMA loop
    int mv = 0; float c_old = 0.f, h_old = 0.f;
    if (tid < 256) {
        mv    = mask[(size_t)brow * T_ + t];
        c_old = c_cur[(size_t)brow * H_ + jcol];
        h_old = bf2f(h_in[(size_t)brow * H_ + jcol]);
    }

    // ---- GEMM: wave w accumulates its 6-kc slice for 2 m-tiles x 2 n-tiles ----
    f32x4 acc00 = {0,0,0,0}, acc01 = {0,0,0,0}, acc10 = {0,0,0,0}, acc11 = {0,0,0,0};
    const unsigned short* bp0 = Wpk + (((size_t)(cg * 2 + 0) * KC_N) * 64 + l) * 8;
    const unsigned short* bp1 = Wpk + (((size_t)(cg * 2 + 1) * KC_N) * 64 + l) * 8;
    const int r0 = b0g + l15;            // m-tile 0 row
    const int r1 = b0g + 16 + l15;       // m-tile 1 row

    #pragma unroll
    for (int i = 0; i < 6; ++i) {
        const int kc = w * 6 + i;
        // B fragments (one coalesced dwordx4 each; L2-resident per XCD)
        s16x8 b0 = *reinterpret_cast<const s16x8*>(bp0 + (size_t)kc * 512);
        s16x8 b1 = *reinterpret_cast<const s16x8*>(bp1 + (size_t)kc * 512);
        // A fragments for both m-tiles
        s16x8 a0, a1;
        if (kc < 16) {                   // x part: f32 -> bf16 in-register
            const float* xp0 = x + ((size_t)r0 * T_ + t) * D_ + kc * 32 + quad * 8;
            const float* xp1 = x + ((size_t)r1 * T_ + t) * D_ + kc * 32 + quad * 8;
            float4 v0 = *reinterpret_cast<const float4*>(xp0);
            float4 v1 = *reinterpret_cast<const float4*>(xp0 + 4);
            float4 v2 = *reinterpret_cast<const float4*>(xp1);
            float4 v3 = *reinterpret_cast<const float4*>(xp1 + 4);
            a0 = cvt8(v0, v1);
            a1 = cvt8(v2, v3);
        } else {                         // h part: bf16 direct
            const int hk = (kc - 16) * 32 + quad * 8;
            a0 = *reinterpret_cast<const s16x8*>(h_in + (size_t)r0 * H_ + hk);
            a1 = *reinterpret_cast<const s16x8*>(h_in + (size_t)r1 * H_ + hk);
        }
        acc00 = __builtin_amdgcn_mfma_f32_16x16x32_bf16(a0, b0, acc00, 0, 0, 0);
        acc01 = __builtin_amdgcn_mfma_f32_16x16x32_bf16(a0, b1, acc01, 0, 0, 0);
        acc10 = __builtin_amdgcn_mfma_f32_16x16x32_bf16(a1, b0, acc10, 0, 0, 0);
        acc11 = __builtin_amdgcn_mfma_f32_16x16x32_bf16(a1, b1, acc11, 0, 0, 0);
    }
    // C/D layout: col = lane&15, row = quad*4 + reg (m89-verified)
    #pragma unroll
    for (int r = 0; r < 4; ++r) {
        Dls[w][quad * 4 + r][l15]           = acc00[r];
        Dls[w][quad * 4 + r][16 + l15]      = acc01[r];
        Dls[w][16 + quad * 4 + r][l15]      = acc10[r];
        Dls[w][16 + quad * 4 + r][16 + l15] = acc11[r];
    }
    __syncthreads();

    // ---- epilogue: reduce 8 k-slices, fused LSTM cell update ----
    if (tid < 256) {
        f32x4 g = (f32x4){0,0,0,0};
        #pragma unroll
        for (int ww = 0; ww < 8; ++ww)
            g += *reinterpret_cast<f32x4*>(&Dls[ww][b_l][u * 4]);
        float4 bias = *reinterpret_cast<const float4*>(bias_p + cg * 32 + u * 4);
        float gi = sigm  (g[0] + bias.x);
        float gf = sigm  (g[1] + bias.y);
        float gg = tanh_f(g[2] + bias.z);
        float go = sigm  (g[3] + bias.w);
        float c_new = gf * c_old + gi * gg;
        float h_new = go * tanh_f(c_new);
        float h2 = mv ? h_new : h_old;
        float c2 = mv ? c_new : c_old;
        const size_t sidx = (size_t)brow * H_ + jcol;
        c_cur[sidx] = c2;
        h_out[sidx] = f2bf(h2);                      // next step reads h_out
        out[((size_t)brow * T_ + t) * H_ + jcol] = h2;
    }
}

extern "C" void kernel_launch(void* const* d_in, const int* in_sizes, int n_in,
                              void* d_out, int out_size, void* d_ws, size_t ws_size,
                              hipStream_t stream)
{
    const float* x    = (const float*)d_in[0];
    const int*   mask = (const int*)d_in[1];
    const float* W_ih = (const float*)d_in[2];
    const float* W_hh = (const float*)d_in[3];
    const float* b_ih = (const float*)d_in[4];
    const float* b_hh = (const float*)d_in[5];
    const float* h0   = (const float*)d_in[6];
    const float* c0   = (const float*)d_in[7];
    float* out = (float*)d_out;

    // ws layout (~13 MB total)
    char* wsb = (char*)d_ws;
    unsigned short* Wpk    = (unsigned short*)(wsb);             // 12,582,912 B
    float*          bias_p = (float*)(wsb + 12582912);           //     16,384 B
    unsigned short* h_a    = (unsigned short*)(wsb + 12599296);  //    131,072 B
    unsigned short* h_b    = (unsigned short*)(wsb + 12730368);  //    131,072 B
    float*          c_cur  = (float*)(wsb + 12861440);           //    262,144 B

    // re-poisoned every call -> re-pack every call
    pack_w<<<24576, 256, 0, stream>>>(W_ih, W_hh, Wpk);
    init_state<<<256, 256, 0, stream>>>(h0, c0, b_ih, b_hh, h_a, c_cur, bias_p);

    dim3 grid(128, 2);
    for (int t = 0; t < T_; ++t) {
        const unsigned short* hin = (t & 1) ? h_b : h_a;
        unsigned short*      hout = (t & 1) ? h_a : h_b;
        lstm_step2<<<grid, 512, 0, stream>>>(x, mask, Wpk, bias_p, hin, hout, c_cur, out, t);
    }
}

// Round 9
// 3268.296 us; speedup vs baseline: 262.0503x; 1.4428x over previous
//
#include <hip/hip_runtime.h>

#define B_   64
#define T_   512
#define D_   512
#define H_   1024
#define G4   4096      // 4*H
#define KTOT 1536      // D + H
#define KC_N 48        // KTOT / 32
#define AP   1544      // padded LDS A-row stride (1536 + 8): breaks 32-bank aliasing

typedef float f32x4 __attribute__((ext_vector_type(4)));
typedef short s16x8 __attribute__((ext_vector_type(8)));

__device__ __forceinline__ unsigned short f2bf(float f) {
    unsigned int u = __float_as_uint(f);
    u = (u + 0x7fffu + ((u >> 16) & 1u)) >> 16;   // RNE
    return (unsigned short)u;
}
__device__ __forceinline__ float bf2f(unsigned short h) {
    return __uint_as_float(((unsigned int)h) << 16);
}
__device__ __forceinline__ float sigm(float x) { return 1.f / (1.f + __expf(-x)); }
__device__ __forceinline__ float tanh_f(float x) { return 1.f - 2.f / (__expf(2.f * x) + 1.f); }

// Pack [W_ih | W_hh] into exact MFMA B-fragment order, bf16, with gate-interleaved
// columns: packed col n = 4*j_hidden + gate  (so one block owns all 4 gates of a j).
// Layout: Wpk[(((c*48 + kc)*64 + lane))*8 + j] = W[row(n)][k], n = c*16 + (lane&15),
// k = kc*32 + (lane>>4)*8 + j.  => per-wave b-frag load is one coalesced dwordx4.
__global__ __launch_bounds__(256) void pack_w(const float* __restrict__ W_ih,
                                              const float* __restrict__ W_hh,
                                              unsigned short* __restrict__ Wpk) {
    int tid = blockIdx.x * 256 + threadIdx.x;        // [0, 256*48*64*8)
    int j    = tid & 7;
    int lane = (tid >> 3) & 63;
    int rest = tid >> 9;
    int kc = rest % KC_N;
    int c  = rest / KC_N;
    int npk = c * 16 + (lane & 15);
    int jh = npk >> 2, g = npk & 3;
    int row = g * H_ + jh;                           // torch gate order i,f,g,o
    int k = kc * 32 + (lane >> 4) * 8 + j;
    float v = (k < D_) ? W_ih[row * D_ + k] : W_hh[row * H_ + (k - D_)];
    Wpk[tid] = f2bf(v);
}

__global__ __launch_bounds__(256) void init_state(const float* __restrict__ h0,
                                                  const float* __restrict__ c0,
                                                  const float* __restrict__ b_ih,
                                                  const float* __restrict__ b_hh,
                                                  unsigned short* __restrict__ h_a,
                                                  float* __restrict__ c_cur,
                                                  float* __restrict__ bias_p) {
    int tid = blockIdx.x * 256 + threadIdx.x;        // 65536
    int j = tid & (H_ - 1);
    h_a[tid]  = f2bf(h0[j]);
    c_cur[tid] = c0[j];
    if (tid < G4) {                                  // bias in packed-col order
        int jh = tid >> 2, g = tid & 3;
        bias_p[tid] = b_ih[g * H_ + jh] + b_hh[g * H_ + jh];
    }
}

// One timestep: gates = [x_t | h] (16x1536) x Wpk-slice (1536x64 packed cols),
// then fused LSTM cell update. Grid (64 gate-blocks, 4 batch-blocks), 256 thr.
// R9 deltas vs the 3451us baseline (structure-preserving latency overlaps):
//  (1) T14 split: h-loads issued FIRST, x cvt work hides their latency,
//      h LDS-writes after.  (2) first-8 B-fragments prefetched pre-barrier.
//  (3) unroll 8 (was 4) on the weight-stream MFMA loop.
__global__ __launch_bounds__(256) void lstm_step(
    const float* __restrict__ x, const int* __restrict__ mask,
    const unsigned short* __restrict__ Wpk, const float* __restrict__ bias_p,
    const unsigned short* __restrict__ h_in, unsigned short* __restrict__ h_out,
    float* __restrict__ c_cur, float* __restrict__ out, int t)
{
    __shared__ unsigned short At[16 * AP];   // [x_t | h] tile, bf16, padded rows
    __shared__ float Dl[16][66];             // gates f32, padded

    const int tid = threadIdx.x;
    const int b0 = blockIdx.y * 16;
    const int bx = blockIdx.x;

    const int w = tid >> 6, l = tid & 63;
    const int quad = l >> 4, l15 = l & 15;
    const int cgrp = bx * 4 + w;             // global 16-col group [0,256)
    const unsigned short* bp = Wpk + ((size_t)(cgrp * KC_N) * 64 + l) * 8;

    // ---- B prefetch: first 8 fragments (independent of LDS staging) ----
    s16x8 bpre[8];
    #pragma unroll
    for (int i = 0; i < 8; ++i)
        bpre[i] = *reinterpret_cast<const s16x8*>(bp + (size_t)i * 512);

    // ---- T14 split: issue h loads into registers FIRST ----
    uint4 hreg[8];
    #pragma unroll
    for (int i = 0; i < 8; ++i) {
        int e = i * 256 + tid;               // [0, 2048): 16 rows x 128 chunks of 8
        int r = e >> 7, c8 = e & 127;
        hreg[i] = *reinterpret_cast<const uint4*>(h_in + (b0 + r) * H_ + c8 * 8);
    }

    // ---- stage x_t slice (fp32 -> bf16): the compute that hides h latency ----
    #pragma unroll
    for (int i = 0; i < 8; ++i) {
        int e = i * 256 + tid;               // [0, 2048): 16 rows x 128 float4
        int r = e >> 7, c4 = e & 127;
        float4 v = *reinterpret_cast<const float4*>(x + ((b0 + r) * T_ + t) * D_ + c4 * 4);
        unsigned int lo = ((unsigned int)f2bf(v.y) << 16) | f2bf(v.x);
        unsigned int hi = ((unsigned int)f2bf(v.w) << 16) | f2bf(v.z);
        *reinterpret_cast<uint2*>(&At[r * AP + c4 * 4]) = make_uint2(lo, hi);
    }
    // ---- write h to LDS (loads long since landed) ----
    #pragma unroll
    for (int i = 0; i < 8; ++i) {
        int e = i * 256 + tid;
        int r = e >> 7, c8 = e & 127;
        *reinterpret_cast<uint4*>(&At[r * AP + D_ + c8 * 8]) = hreg[i];
    }
    __syncthreads();

    // ---- MFMA: wave w computes 16 batch x 16 packed-gate-cols ----
    f32x4 acc = {0.f, 0.f, 0.f, 0.f};
    const unsigned short* atp = &At[l15 * AP + quad * 8];   // A[m=lane&15][k=quad*8+j]
    #pragma unroll
    for (int kc = 0; kc < 8; ++kc) {         // prefetched B, literal indices
        s16x8 af = *reinterpret_cast<const s16x8*>(atp + kc * 32);
        acc = __builtin_amdgcn_mfma_f32_16x16x32_bf16(af, bpre[kc], acc, 0, 0, 0);
    }
    #pragma unroll 8
    for (int kc = 8; kc < KC_N; ++kc) {
        s16x8 af = *reinterpret_cast<const s16x8*>(atp + kc * 32);
        s16x8 bf = *reinterpret_cast<const s16x8*>(bp + (size_t)kc * 512);
        acc = __builtin_amdgcn_mfma_f32_16x16x32_bf16(af, bf, acc, 0, 0, 0);
    }
    // C/D layout: col = lane&15, row = quad*4 + reg  (m89-verified)
    #pragma unroll
    for (int r = 0; r < 4; ++r)
        Dl[quad * 4 + r][w * 16 + l15] = acc[r];
    __syncthreads();

    // ---- epilogue: thread -> (batch b, hidden u); 4 gates are cols 4u..4u+3 ----
    const int b = tid >> 4, u = tid & 15;
    const int jh = bx * 16 + u;
    float4 bias = *reinterpret_cast<const float4*>(bias_p + bx * 64 + u * 4);
    float gi = sigm (Dl[b][u * 4 + 0] + bias.x);
    float gf = sigm (Dl[b][u * 4 + 1] + bias.y);
    float gg = tanh_f(Dl[b][u * 4 + 2] + bias.z);
    float go = sigm (Dl[b][u * 4 + 3] + bias.w);

    const int sidx = (b0 + b) * H_ + jh;
    float c_old = c_cur[sidx];
    float h_old = bf2f(At[b * AP + D_ + jh]);      // previous h from LDS stage
    float c_new = gf * c_old + gi * gg;
    float h_new = go * tanh_f(c_new);
    int m = mask[(b0 + b) * T_ + t];
    float h2 = m ? h_new : h_old;
    float c2 = m ? c_new : c_old;
    c_cur[sidx] = c2;
    h_out[sidx] = f2bf(h2);                        // always write: next step reads h_out
    out[((size_t)(b0 + b) * T_ + t) * H_ + jh] = h2;
}

extern "C" void kernel_launch(void* const* d_in, const int* in_sizes, int n_in,
                              void* d_out, int out_size, void* d_ws, size_t ws_size,
                              hipStream_t stream)
{
    const float* x    = (const float*)d_in[0];
    const int*   mask = (const int*)d_in[1];
    const float* W_ih = (const float*)d_in[2];
    const float* W_hh = (const float*)d_in[3];
    const float* b_ih = (const float*)d_in[4];
    const float* b_hh = (const float*)d_in[5];
    const float* h0   = (const float*)d_in[6];
    const float* c0   = (const float*)d_in[7];
    float* out = (float*)d_out;

    // ws layout (~13 MB total)
    char* wsb = (char*)d_ws;
    unsigned short* Wpk    = (unsigned short*)(wsb);             // 12,582,912 B
    float*          bias_p = (float*)(wsb + 12582912);           //     16,384 B
    unsigned short* h_a    = (unsigned short*)(wsb + 12599296);  //    131,072 B
    unsigned short* h_b    = (unsigned short*)(wsb + 12730368);  //    131,072 B
    float*          c_cur  = (float*)(wsb + 12861440);           //    262,144 B

    // re-poisoned every call -> re-pack every call (one-time cost ~50-100 us)
    pack_w<<<24576, 256, 0, stream>>>(W_ih, W_hh, Wpk);
    init_state<<<256, 256, 0, stream>>>(h0, c0, b_ih, b_hh, h_a, c_cur, bias_p);

    dim3 grid(64, 4);
    for (int t = 0; t < T_; ++t) {
        const unsigned short* hin = (t & 1) ? h_b : h_a;
        unsigned short*      hout = (t & 1) ? h_a : h_b;
        lstm_step<<<grid, 256, 0, stream>>>(x, mask, Wpk, bias_p, hin, hout, c_cur, out, t);
    }
}